// Round 1
// baseline (649.410 us; speedup 1.0000x reference)
//
#include <hip/hip_runtime.h>
#include <stdint.h>

// Problem constants (reference: B=4, N=8192, C=64, OUT=64, KNN=36)
#define BB 4
#define NN 8192
#define CC 64
#define OUTD 64
#define KK 36
#define NPTS (BB * NN)          // 32768
#define BINBASE 3008            // (0x800 + 120*8): covers d^2 in [2^-7, 2^9) w/ 3 mantissa bits
#define NBIN 129                // bins 0..128 (0 and 128 are clamp catch-alls)

static __device__ __forceinline__ int laneid() { return threadIdx.x & 63; }
static __device__ __forceinline__ int waveid_uniform() {
    return __builtin_amdgcn_readfirstlane((int)(threadIdx.x >> 6));
}

// ---------------------------------------------------------------------------
// Kernel 1: v_feat = relu([feature, xyz] @ W_v + b_v)  and pack xyzw=(x,y,z,|p|^2)
// One wave per point, lane = output channel. grid = NPTS/4 blocks of 256.
// ---------------------------------------------------------------------------
__global__ __launch_bounds__(256) void k_vfeat(
    const float* __restrict__ feat, const float* __restrict__ xyz,
    const float* __restrict__ Wv, const float* __restrict__ bv,
    float* __restrict__ vfeat, float4* __restrict__ xyzw)
{
    __shared__ float fb[4][64];
    const int lane = laneid();
    const int wv = waveid_uniform();
    const int p = blockIdx.x * 4 + wv;          // 0..NPTS-1

    float f = feat[p * CC + lane];
    fb[wv][lane] = f;

    const float x = xyz[p * 3 + 0];
    const float y = xyz[p * 3 + 1];
    const float z = xyz[p * 3 + 2];

    float a = bv[lane];
    #pragma unroll 8
    for (int c = 0; c < CC; ++c)
        a = fmaf(fb[wv][c], Wv[c * OUTD + lane], a);
    a = fmaf(x, Wv[64 * OUTD + lane], a);
    a = fmaf(y, Wv[65 * OUTD + lane], a);
    a = fmaf(z, Wv[66 * OUTD + lane], a);
    a = fmaxf(a, 0.0f);
    vfeat[p * OUTD + lane] = a;

    if (lane == 0) {
        float sq = (x * x + y * y) + z * z;
        xyzw[p] = make_float4(x, y, z, sq);
    }
}

// ---------------------------------------------------------------------------
// Kernel 2: 36-NN via per-query float-bit histogram selection.
// Block = 256 threads = 4 waves sharing the SAME 64 queries (lane = query),
// each wave scans a 2048-candidate segment. grid = NPTS/64 = 512 blocks.
// Output: unordered set of 36 nearest global row ids per query (order is
// irrelevant downstream: softmax-weighted sum is permutation invariant).
// Tie-break matches lax.top_k: (distance, then smaller index).
// ---------------------------------------------------------------------------
static __device__ __forceinline__ void dist_bin(
    float4 Q, float4 Cd, uint32_t* ordOut, int* binOut)
{
    float dot = fmaf(Q.x, Cd.x, fmaf(Q.y, Cd.y, Q.z * Cd.z));
    float d = fmaf(-2.0f, dot, Q.w + Cd.w);
    d = fmaxf(d, 0.0f);
    uint32_t ord = __float_as_uint(d) ^ 0x80000000u;   // monotone key for d>=+0
    int bin = (int)(ord >> 20) - BINBASE;
    bin = bin < 0 ? 0 : (bin > 128 ? 128 : bin);
    *ordOut = ord; *binOut = bin;
}

__global__ __launch_bounds__(256) void k_knn(
    const float4* __restrict__ xyzw, int* __restrict__ idx_ws)
{
    __shared__ __align__(16) uint32_t hist[64 * NBIN];  // 33 KB; reused as buf in pass 2
    __shared__ int binB[64];
    __shared__ int cumLoA[64];
    __shared__ uint32_t bufCnt[64];
    __shared__ uint32_t dirCnt[64];

    const int lane = laneid();
    const int wv = waveid_uniform();
    const int batch = blockIdx.x >> 7;             // 128 blocks per batch
    const int qbase = (blockIdx.x & 127) << 6;
    const int q = qbase + lane;                    // local query id 0..8191
    const float4* __restrict__ xw = xyzw + batch * NN;

    const float4 Q = xw[q];

    for (int i = threadIdx.x; i < 64 * NBIN; i += 256) hist[i] = 0u;
    if (threadIdx.x < 64) { bufCnt[threadIdx.x] = 0u; dirCnt[threadIdx.x] = 0u; }
    __syncthreads();

    const int j0 = wv * 2048;

    // ---- pass 1: histogram of distance bits ----
    #pragma unroll 4
    for (int j = j0; j < j0 + 2048; ++j) {
        float4 Cd = xw[j];                         // wave-uniform -> s_load_dwordx4
        uint32_t ord; int bin;
        dist_bin(Q, Cd, &ord, &bin);
        atomicAdd(&hist[lane * NBIN + bin], 1u);
    }
    __syncthreads();

    // ---- find crossing bin (threads 0..63, one query each) ----
    if (threadIdx.x < 64) {
        int cum = 0, Bq = 128, cl = 0;
        for (int b2 = 0; b2 < NBIN; ++b2) {
            int c = (int)hist[threadIdx.x * NBIN + b2];
            if (cum + c >= KK) { Bq = b2; cl = cum; break; }
            cum += c;
        }
        binB[threadIdx.x] = Bq;
        cumLoA[threadIdx.x] = cl;
    }
    __syncthreads();

    // ---- pass 2: direct-emit strict members; buffer boundary-bin members ----
    unsigned long long* buf = (unsigned long long*)hist;  // 64 queries x 64 keys
    const int Bq = binB[lane];
    const int grow = batch * NN + q;
    #pragma unroll 4
    for (int j = j0; j < j0 + 2048; ++j) {
        float4 Cd = xw[j];
        uint32_t ord; int bin;
        dist_bin(Q, Cd, &ord, &bin);
        if (bin < Bq) {
            uint32_t pos = atomicAdd(&dirCnt[lane], 1u);
            if (pos < KK) idx_ws[grow * KK + (int)pos] = batch * NN + j;
        } else if (bin == Bq) {
            uint32_t pos = atomicAdd(&bufCnt[lane], 1u);
            if (pos < 64u) buf[lane * 64 + (int)pos] =
                ((unsigned long long)ord << 32) | (uint32_t)j;
        }
    }
    __syncthreads();

    // ---- final: pick (36 - cumLo) smallest exact keys from boundary bin ----
    if (threadIdx.x < 64) {
        const int t = threadIdx.x;
        const int q2 = qbase + t;
        const int grow2 = batch * NN + q2;
        const int cl = cumLoA[t];
        const int r = KK - cl;
        const int M = min((int)bufCnt[t], 64);
        unsigned long long* mybuf = buf + t * 64;
        const int outp = grow2 * KK + cl;
        for (int i = 0; i < r; ++i) {
            unsigned long long best = ~0ULL; int bi = -1;
            for (int u = 0; u < M; ++u) {
                unsigned long long v = mybuf[u];
                if (v < best) { best = v; bi = u; }
            }
            int jj;
            if (bi >= 0) { mybuf[bi] = ~0ULL; jj = (int)(best & 0xFFFFFFFFu); }
            else jj = q2;                            // pathological fallback
            if (jj < 0 || jj >= NN) jj = q2;
            idx_ws[outp + i] = batch * NN + jj;
        }
    }
}

// ---------------------------------------------------------------------------
// Kernel 3: attention. One wave per point (lane = channel).
//   logits_k = <feat[n], feat[idx_k]>  -> online softmax ->
//   acc = sum_k w_k * vfeat[idx_k]     -> out = acc @ W_suf + b_suf
// grid = NPTS/4 blocks of 256.
// ---------------------------------------------------------------------------
__global__ __launch_bounds__(256) void k_att(
    const float* __restrict__ feat, const float* __restrict__ vfeat,
    const int* __restrict__ idxw, const float* __restrict__ Wsuf,
    const float* __restrict__ bsuf, float* __restrict__ out)
{
    __shared__ float logits[4][40];
    __shared__ float accb[4][64];
    const int lane = laneid();
    const int wv = waveid_uniform();
    const int p = blockIdx.x * 4 + wv;

    const float f = feat[p * CC + lane];
    float m = -1e30f, s = 0.0f;

    for (int k = 0; k < KK; ++k) {
        int j = idxw[p * KK + k];                  // wave-uniform -> s_load
        float g = feat[j * CC + lane];
        float prod = f * g;
        #pragma unroll
        for (int off = 32; off > 0; off >>= 1)
            prod += __shfl_xor(prod, off, 64);
        if (lane == (k & 63)) logits[wv][k] = prod;
        float nm = fmaxf(m, prod);
        s = s * __expf(m - nm) + __expf(prod - nm);
        m = nm;
    }
    const float inv = 1.0f / s;

    float acc = 0.0f;
    for (int k = 0; k < KK; ++k) {
        int j = idxw[p * KK + k];
        float w = __expf(logits[wv][k] - m);
        float v = vfeat[j * OUTD + lane];
        acc = fmaf(w, v, acc);
    }
    acc *= inv;
    accb[wv][lane] = acc;

    float o = bsuf[lane];
    #pragma unroll 8
    for (int c = 0; c < OUTD; ++c)
        o = fmaf(accb[wv][c], Wsuf[c * OUTD + lane], o);
    out[p * OUTD + lane] = o;

    if (p == 0 && lane == 0) out[NPTS * OUTD] = (float)NN;  // output 1: scalar N
}

// ---------------------------------------------------------------------------
extern "C" void kernel_launch(void* const* d_in, const int* in_sizes, int n_in,
                              void* d_out, int out_size, void* d_ws, size_t ws_size,
                              hipStream_t stream)
{
    const float* feat = (const float*)d_in[0];
    const float* xyz  = (const float*)d_in[1];
    const float* Wv   = (const float*)d_in[2];
    const float* bv   = (const float*)d_in[3];
    const float* Wsuf = (const float*)d_in[4];
    const float* bsuf = (const float*)d_in[5];
    float* out = (float*)d_out;

    char* ws = (char*)d_ws;
    float4* xyzw = (float4*)ws;                               // 512 KB
    float*  vfeat = (float*)(ws + (512 << 10));               // 8 MB
    int*    idxw  = (int*)(ws + (512 << 10) + (8 << 20));     // 4.5 MB

    k_vfeat<<<NPTS / 4, 256, 0, stream>>>(feat, xyz, Wv, bv, vfeat, xyzw);
    k_knn  <<<NPTS / 64, 256, 0, stream>>>(xyzw, idxw);
    k_att  <<<NPTS / 4, 256, 0, stream>>>(feat, vfeat, idxw, Wsuf, bsuf, out);
}

// Round 2
// 378.847 us; speedup vs baseline: 1.7142x; 1.7142x over previous
//
#include <hip/hip_runtime.h>
#include <stdint.h>

// Problem constants (reference: B=4, N=8192, C=64, OUT=64, KNN=36)
#define BB 4
#define NN 8192
#define CC 64
#define OUTD 64
#define KK 36
#define NPTS (BB * NN)          // 32768
#define BINBASE 3008            // (0x800 + 120*8): covers d^2 in [2^-7, 2^9) w/ 3 mantissa bits
#define NBIN 129                // bins 0..128 (0 and 128 are clamp catch-alls)

static __device__ __forceinline__ int laneid() { return threadIdx.x & 63; }
static __device__ __forceinline__ int waveid_uniform() {
    return __builtin_amdgcn_readfirstlane((int)(threadIdx.x >> 6));
}

// ---------------------------------------------------------------------------
// Kernel 1: v_feat = relu([feature, xyz] @ W_v + b_v)  and pack xyzw=(x,y,z,|p|^2)
// One wave per point, lane = output channel. grid = NPTS/4 blocks of 256.
// ---------------------------------------------------------------------------
__global__ __launch_bounds__(256) void k_vfeat(
    const float* __restrict__ feat, const float* __restrict__ xyz,
    const float* __restrict__ Wv, const float* __restrict__ bv,
    float* __restrict__ vfeat, float4* __restrict__ xyzw)
{
    __shared__ float fb[4][64];
    const int lane = laneid();
    const int wv = waveid_uniform();
    const int p = blockIdx.x * 4 + wv;          // 0..NPTS-1

    float f = feat[p * CC + lane];
    fb[wv][lane] = f;

    const float x = xyz[p * 3 + 0];
    const float y = xyz[p * 3 + 1];
    const float z = xyz[p * 3 + 2];

    float a = bv[lane];
    #pragma unroll 8
    for (int c = 0; c < CC; ++c)
        a = fmaf(fb[wv][c], Wv[c * OUTD + lane], a);
    a = fmaf(x, Wv[64 * OUTD + lane], a);
    a = fmaf(y, Wv[65 * OUTD + lane], a);
    a = fmaf(z, Wv[66 * OUTD + lane], a);
    a = fmaxf(a, 0.0f);
    vfeat[p * OUTD + lane] = a;

    if (lane == 0) {
        float sq = (x * x + y * y) + z * z;
        xyzw[p] = make_float4(x, y, z, sq);
    }
}

// ---------------------------------------------------------------------------
// Kernel 2: 36-NN via per-query float-bit histogram selection.
// Block = 1024 threads = 16 waves sharing the SAME 64 queries (lane = query),
// each wave scans a 512-candidate segment. grid = NPTS/64 = 512 blocks.
// 2 blocks/CU x 1024 thr = 2048 thr/CU = full occupancy (VGPR<=64 required).
// Output: unordered set of 36 nearest global row ids per query (order is
// irrelevant downstream: softmax-weighted sum is permutation invariant).
// Tie-break matches lax.top_k: (distance, then smaller index).
// ---------------------------------------------------------------------------
static __device__ __forceinline__ void dist_bin(
    float4 Q, float4 Cd, uint32_t* ordOut, int* binOut)
{
    float dot = fmaf(Q.x, Cd.x, fmaf(Q.y, Cd.y, Q.z * Cd.z));
    float d = fmaf(-2.0f, dot, Q.w + Cd.w);
    d = fmaxf(d, 0.0f);
    uint32_t ord = __float_as_uint(d) ^ 0x80000000u;   // monotone key for d>=+0
    int bin = (int)(ord >> 20) - BINBASE;
    bin = bin < 0 ? 0 : (bin > 128 ? 128 : bin);
    *ordOut = ord; *binOut = bin;
}

__global__ __launch_bounds__(1024) void k_knn(
    const float4* __restrict__ xyzw, int* __restrict__ idx_ws)
{
    __shared__ __align__(16) uint32_t hist[64 * NBIN];  // 33 KB; reused as buf in pass 2
    __shared__ int binB[64];
    __shared__ int cumLoA[64];
    __shared__ uint32_t bufCnt[64];
    __shared__ uint32_t dirCnt[64];

    const int lane = laneid();
    const int wv = waveid_uniform();               // 0..15
    const int batch = blockIdx.x >> 7;             // 128 blocks per batch
    const int qbase = (blockIdx.x & 127) << 6;
    const int q = qbase + lane;                    // local query id 0..8191
    const float4* __restrict__ xw = xyzw + batch * NN;

    const float4 Q = xw[q];

    for (int i = threadIdx.x; i < 64 * NBIN; i += 1024) hist[i] = 0u;
    if (threadIdx.x < 64) { bufCnt[threadIdx.x] = 0u; dirCnt[threadIdx.x] = 0u; }
    __syncthreads();

    const int j0 = wv * 512;

    // ---- pass 1: histogram of distance bits ----
    #pragma unroll 4
    for (int j = j0; j < j0 + 512; ++j) {
        float4 Cd = xw[j];                         // wave-uniform -> s_load_dwordx4
        uint32_t ord; int bin;
        dist_bin(Q, Cd, &ord, &bin);
        atomicAdd(&hist[lane * NBIN + bin], 1u);
    }
    __syncthreads();

    // ---- find crossing bin (threads 0..63, one query each) ----
    if (threadIdx.x < 64) {
        int cum = 0, Bq = 128, cl = 0;
        for (int b2 = 0; b2 < NBIN; ++b2) {
            int c = (int)hist[threadIdx.x * NBIN + b2];
            if (cum + c >= KK) { Bq = b2; cl = cum; break; }
            cum += c;
        }
        binB[threadIdx.x] = Bq;
        cumLoA[threadIdx.x] = cl;
    }
    __syncthreads();

    // ---- pass 2: direct-emit strict members; buffer boundary-bin members ----
    unsigned long long* buf = (unsigned long long*)hist;  // 64 queries x 64 keys
    const int Bq = binB[lane];
    const int grow = batch * NN + q;
    #pragma unroll 4
    for (int j = j0; j < j0 + 512; ++j) {
        float4 Cd = xw[j];
        uint32_t ord; int bin;
        dist_bin(Q, Cd, &ord, &bin);
        if (bin < Bq) {
            uint32_t pos = atomicAdd(&dirCnt[lane], 1u);
            if (pos < KK) idx_ws[grow * KK + (int)pos] = batch * NN + j;
        } else if (bin == Bq) {
            uint32_t pos = atomicAdd(&bufCnt[lane], 1u);
            if (pos < 64u) buf[lane * 64 + (int)pos] =
                ((unsigned long long)ord << 32) | (uint32_t)j;
        }
    }
    __syncthreads();

    // ---- final: pick (36 - cumLo) smallest exact keys from boundary bin ----
    if (threadIdx.x < 64) {
        const int t = threadIdx.x;
        const int q2 = qbase + t;
        const int grow2 = batch * NN + q2;
        const int cl = cumLoA[t];
        const int r = KK - cl;
        const int M = min((int)bufCnt[t], 64);
        unsigned long long* mybuf = buf + t * 64;
        const int outp = grow2 * KK + cl;
        for (int i = 0; i < r; ++i) {
            unsigned long long best = ~0ULL; int bi = -1;
            for (int u = 0; u < M; ++u) {
                unsigned long long v = mybuf[u];
                if (v < best) { best = v; bi = u; }
            }
            int jj;
            if (bi >= 0) { mybuf[bi] = ~0ULL; jj = (int)(best & 0xFFFFFFFFu); }
            else jj = q2;                            // pathological fallback
            if (jj < 0 || jj >= NN) jj = q2;
            idx_ws[outp + i] = batch * NN + jj;
        }
    }
}

// ---------------------------------------------------------------------------
// Kernel 3: attention. One wave per point (lane = channel).
//   logits_k = <feat[n], feat[idx_k]>  -> online softmax ->
//   acc = sum_k w_k * vfeat[idx_k]     -> out = acc @ W_suf + b_suf
// grid = NPTS/4 blocks of 256.
// ---------------------------------------------------------------------------
__global__ __launch_bounds__(256) void k_att(
    const float* __restrict__ feat, const float* __restrict__ vfeat,
    const int* __restrict__ idxw, const float* __restrict__ Wsuf,
    const float* __restrict__ bsuf, float* __restrict__ out)
{
    __shared__ float logits[4][40];
    __shared__ float accb[4][64];
    const int lane = laneid();
    const int wv = waveid_uniform();
    const int p = blockIdx.x * 4 + wv;

    const float f = feat[p * CC + lane];
    float m = -1e30f, s = 0.0f;

    for (int k = 0; k < KK; ++k) {
        int j = idxw[p * KK + k];                  // wave-uniform -> s_load
        float g = feat[j * CC + lane];
        float prod = f * g;
        #pragma unroll
        for (int off = 32; off > 0; off >>= 1)
            prod += __shfl_xor(prod, off, 64);
        if (lane == (k & 63)) logits[wv][k] = prod;
        float nm = fmaxf(m, prod);
        s = s * __expf(m - nm) + __expf(prod - nm);
        m = nm;
    }
    const float inv = 1.0f / s;

    float acc = 0.0f;
    for (int k = 0; k < KK; ++k) {
        int j = idxw[p * KK + k];
        float w = __expf(logits[wv][k] - m);
        float v = vfeat[j * OUTD + lane];
        acc = fmaf(w, v, acc);
    }
    acc *= inv;
    accb[wv][lane] = acc;

    float o = bsuf[lane];
    #pragma unroll 8
    for (int c = 0; c < OUTD; ++c)
        o = fmaf(accb[wv][c], Wsuf[c * OUTD + lane], o);
    out[p * OUTD + lane] = o;

    if (p == 0 && lane == 0) out[NPTS * OUTD] = (float)NN;  // output 1: scalar N
}

// ---------------------------------------------------------------------------
extern "C" void kernel_launch(void* const* d_in, const int* in_sizes, int n_in,
                              void* d_out, int out_size, void* d_ws, size_t ws_size,
                              hipStream_t stream)
{
    const float* feat = (const float*)d_in[0];
    const float* xyz  = (const float*)d_in[1];
    const float* Wv   = (const float*)d_in[2];
    const float* bv   = (const float*)d_in[3];
    const float* Wsuf = (const float*)d_in[4];
    const float* bsuf = (const float*)d_in[5];
    float* out = (float*)d_out;

    char* ws = (char*)d_ws;
    float4* xyzw = (float4*)ws;                               // 512 KB
    float*  vfeat = (float*)(ws + (512 << 10));               // 8 MB
    int*    idxw  = (int*)(ws + (512 << 10) + (8 << 20));     // 4.5 MB

    k_vfeat<<<NPTS / 4, 256, 0, stream>>>(feat, xyz, Wv, bv, vfeat, xyzw);
    k_knn  <<<NPTS / 64, 1024, 0, stream>>>(xyzw, idxw);
    k_att  <<<NPTS / 4, 256, 0, stream>>>(feat, vfeat, idxw, Wsuf, bsuf, out);
}

// Round 3
// 333.476 us; speedup vs baseline: 1.9474x; 1.1361x over previous
//
#include <hip/hip_runtime.h>
#include <stdint.h>

// Problem constants (reference: B=4, N=8192, C=64, OUT=64, KNN=36)
#define BB 4
#define NN 8192
#define CC 64
#define OUTD 64
#define KK 36
#define NPTS (BB * NN)          // 32768
#define NBIN 129                // bins 0..128 (0 and 128 are clamp catch-alls)
// bin = (float_bits(d2) >> 20) - 960, clamped: covers d^2 in [2^-7, 2^9), 3 mantissa bits

static __device__ __forceinline__ int laneid() { return threadIdx.x & 63; }
static __device__ __forceinline__ int waveid_uniform() {
    return __builtin_amdgcn_readfirstlane((int)(threadIdx.x >> 6));
}

// ---------------------------------------------------------------------------
// Kernel 1: v_feat = relu([feature, xyz] @ W_v + b_v)  and pack xyzw=(x,y,z,|p|^2)
// One wave handles 8 points (shares each Wv row load across 8 accumulators).
// Block = 256 = 4 waves = 32 points. grid = NPTS/32 = 1024 blocks.
// ---------------------------------------------------------------------------
__global__ __launch_bounds__(256) void k_vfeat(
    const float* __restrict__ feat, const float* __restrict__ xyz,
    const float* __restrict__ Wv, const float* __restrict__ bv,
    float* __restrict__ vfeat, float4* __restrict__ xyzw)
{
    __shared__ float fb[4][8][64];
    __shared__ float xb[4][8][3];
    const int lane = laneid();
    const int wv = waveid_uniform();
    const int pbase = blockIdx.x * 32 + wv * 8;

    #pragma unroll
    for (int pp = 0; pp < 8; ++pp)
        fb[wv][pp][lane] = feat[(pbase + pp) * CC + lane];
    if (lane < 24)
        xb[wv][lane / 3][lane % 3] = xyz[pbase * 3 + lane];
    // same-wave LDS write->read: in-order per wave, compiler inserts lgkmcnt

    const float b0 = bv[lane];
    float acc[8];
    #pragma unroll
    for (int pp = 0; pp < 8; ++pp) acc[pp] = b0;

    #pragma unroll 4
    for (int c = 0; c < CC; ++c) {
        float w = Wv[c * OUTD + lane];
        #pragma unroll
        for (int pp = 0; pp < 8; ++pp)
            acc[pp] = fmaf(fb[wv][pp][c], w, acc[pp]);
    }
    const float wx = Wv[64 * OUTD + lane];
    const float wy = Wv[65 * OUTD + lane];
    const float wz = Wv[66 * OUTD + lane];
    #pragma unroll
    for (int pp = 0; pp < 8; ++pp) {
        float a = acc[pp];
        a = fmaf(xb[wv][pp][0], wx, a);
        a = fmaf(xb[wv][pp][1], wy, a);
        a = fmaf(xb[wv][pp][2], wz, a);
        vfeat[(pbase + pp) * OUTD + lane] = fmaxf(a, 0.0f);
    }
    if (lane < 8) {
        float x = xb[wv][lane][0], y = xb[wv][lane][1], z = xb[wv][lane][2];
        float sq = (x * x + y * y) + z * z;
        xyzw[pbase + lane] = make_float4(x, y, z, sq);
    }
}

// ---------------------------------------------------------------------------
// Kernel 2: 36-NN via per-query float-bit histogram selection.
// Block = 1024 threads = 16 waves sharing the SAME 64 queries (lane = query),
// each wave scans a 512-candidate segment. grid = NPTS/64 = 512 blocks.
// Histogram TRANSPOSED: hist[bin][lane] -> bank = lane%32 -> free 2-way only.
// Tie-break matches lax.top_k: (distance-bits, then smaller index).
// ---------------------------------------------------------------------------
__global__ __launch_bounds__(1024) void k_knn(
    const float4* __restrict__ xyzw, int* __restrict__ idx_ws)
{
    __shared__ __align__(16) uint32_t hist[NBIN * 64];  // 33 KB; reused as buf in pass 2
    __shared__ int binB[64];
    __shared__ int cumLoA[64];
    __shared__ uint32_t bufCnt[64];
    __shared__ uint32_t dirCnt[64];

    const int lane = laneid();
    const int wv = waveid_uniform();               // 0..15
    const int batch = blockIdx.x >> 7;             // 128 blocks per batch
    const int qbase = (blockIdx.x & 127) << 6;
    const int q = qbase + lane;                    // local query id 0..8191
    const float4* __restrict__ xw = xyzw + batch * NN;

    const float4 Q = xw[q];

    for (int i = threadIdx.x; i < NBIN * 64; i += 1024) hist[i] = 0u;
    if (threadIdx.x < 64) { bufCnt[threadIdx.x] = 0u; dirCnt[threadIdx.x] = 0u; }
    __syncthreads();

    const int j0 = wv * 512;

    // ---- pass 1: histogram of distance bits ----
    #pragma unroll 4
    for (int j = j0; j < j0 + 512; ++j) {
        float4 Cd = xw[j];                         // wave-uniform -> s_load_dwordx4
        float dot = fmaf(Q.x, Cd.x, fmaf(Q.y, Cd.y, Q.z * Cd.z));
        float d = fmaf(-2.0f, dot, Q.w + Cd.w);
        d = fmaxf(d, 0.0f);
        int bin = (int)(__float_as_uint(d) >> 20) - 960;
        bin = bin < 0 ? 0 : (bin > 128 ? 128 : bin);
        atomicAdd(&hist[bin * 64 + lane], 1u);
    }
    __syncthreads();

    // ---- find crossing bin (threads 0..63, one query each) ----
    if (threadIdx.x < 64) {
        int cum = 0, Bq = 128, cl = 0;
        for (int b2 = 0; b2 < NBIN; ++b2) {
            int c = (int)hist[b2 * 64 + threadIdx.x];
            if (cum + c >= KK) { Bq = b2; cl = cum; break; }
            cum += c;
        }
        binB[threadIdx.x] = Bq;
        cumLoA[threadIdx.x] = cl;
    }
    __syncthreads();

    // ---- pass 2: direct-emit strict members; buffer boundary-bin members ----
    // buf[pos][lane] (transposed): 64 pos x 64 lanes x 8B = 32 KB (inside hist)
    unsigned long long* buf = (unsigned long long*)hist;
    const int Bq = binB[lane];
    const int grow = batch * NN + q;
    #pragma unroll 4
    for (int j = j0; j < j0 + 512; ++j) {
        float4 Cd = xw[j];
        float dot = fmaf(Q.x, Cd.x, fmaf(Q.y, Cd.y, Q.z * Cd.z));
        float d = fmaf(-2.0f, dot, Q.w + Cd.w);
        d = fmaxf(d, 0.0f);
        uint32_t db = __float_as_uint(d);
        int bin = (int)(db >> 20) - 960;
        bin = bin < 0 ? 0 : (bin > 128 ? 128 : bin);
        if (bin < Bq) {
            uint32_t pos = atomicAdd(&dirCnt[lane], 1u);
            if (pos < KK) idx_ws[grow * KK + (int)pos] = batch * NN + j;
        } else if (bin == Bq) {
            uint32_t pos = atomicAdd(&bufCnt[lane], 1u);
            if (pos < 64u) buf[(int)pos * 64 + lane] =
                ((unsigned long long)db << 32) | (uint32_t)j;
        }
    }
    __syncthreads();

    // ---- final: pick (36 - cumLo) smallest exact keys from boundary bin ----
    if (threadIdx.x < 64) {
        const int t = threadIdx.x;
        const int q2 = qbase + t;
        const int grow2 = batch * NN + q2;
        const int cl = cumLoA[t];
        const int r = KK - cl;
        const int M = min((int)bufCnt[t], 64);
        const int outp = grow2 * KK + cl;
        for (int i = 0; i < r; ++i) {
            unsigned long long best = ~0ULL; int bi = -1;
            for (int u = 0; u < M; ++u) {
                unsigned long long v = buf[u * 64 + t];
                if (v < best) { best = v; bi = u; }
            }
            int jj;
            if (bi >= 0) { buf[bi * 64 + t] = ~0ULL; jj = (int)(best & 0xFFFFFFFFu); }
            else jj = q2;                            // pathological fallback
            if (jj < 0 || jj >= NN) jj = q2;
            idx_ws[outp + i] = batch * NN + jj;
        }
    }
}

// ---------------------------------------------------------------------------
// Kernel 3: attention. One wave per point. No serial softmax chain:
//   stage 36 gathered neighbor rows in LDS (stride 65 -> conflict-free),
//   lane k<36 computes logit_k, one butterfly max + one butterfly sum,
//   then lane=channel weighted-V gather + 64x64 projection.
// grid = NPTS/4 blocks of 256. No __syncthreads (waves independent).
// ---------------------------------------------------------------------------
__global__ __launch_bounds__(256) void k_att(
    const float* __restrict__ feat, const float* __restrict__ vfeat,
    const int* __restrict__ idxw, const float* __restrict__ Wsuf,
    const float* __restrict__ bsuf, float* __restrict__ out)
{
    __shared__ float G[4][KK][65];   // 37,440 B
    __shared__ float F[4][64];
    __shared__ float Wb[4][KK];
    __shared__ float accb[4][64];
    const int lane = laneid();
    const int wv = waveid_uniform();
    const int p = blockIdx.x * 4 + wv;
    const int* __restrict__ myidx = idxw + p * KK;

    const float f = feat[p * CC + lane];
    F[wv][lane] = f;

    #pragma unroll 4
    for (int k = 0; k < KK; ++k) {
        int j = myidx[k];                          // wave-uniform -> s_load
        G[wv][k][lane] = feat[j * CC + lane];      // coalesced row gather
    }

    // logits: lane k (<36) sums over channels; G stride 65 = bank-conflict-free
    float logit = -1e30f;
    if (lane < KK) {
        float a = 0.0f;
        #pragma unroll 8
        for (int c = 0; c < CC; ++c)
            a = fmaf(F[wv][c], G[wv][lane][c], a);
        logit = a;
    }
    // softmax across the 36 logit lanes (others contribute -inf / 0)
    float m = logit;
    #pragma unroll
    for (int off = 32; off > 0; off >>= 1)
        m = fmaxf(m, __shfl_xor(m, off, 64));
    float e = (lane < KK) ? __expf(logit - m) : 0.0f;
    float s = e;
    #pragma unroll
    for (int off = 32; off > 0; off >>= 1)
        s += __shfl_xor(s, off, 64);
    if (lane < KK) Wb[wv][lane] = e / s;

    // weighted V gather: lane = channel
    float acc = 0.0f;
    #pragma unroll 4
    for (int k = 0; k < KK; ++k) {
        int j = myidx[k];
        acc = fmaf(Wb[wv][k], vfeat[j * OUTD + lane], acc);
    }
    accb[wv][lane] = acc;

    float o = bsuf[lane];
    #pragma unroll 8
    for (int c = 0; c < OUTD; ++c)
        o = fmaf(accb[wv][c], Wsuf[c * OUTD + lane], o);
    out[p * OUTD + lane] = o;

    if (p == 0 && lane == 0) out[NPTS * OUTD] = (float)NN;  // output 1: scalar N
}

// ---------------------------------------------------------------------------
extern "C" void kernel_launch(void* const* d_in, const int* in_sizes, int n_in,
                              void* d_out, int out_size, void* d_ws, size_t ws_size,
                              hipStream_t stream)
{
    const float* feat = (const float*)d_in[0];
    const float* xyz  = (const float*)d_in[1];
    const float* Wv   = (const float*)d_in[2];
    const float* bv   = (const float*)d_in[3];
    const float* Wsuf = (const float*)d_in[4];
    const float* bsuf = (const float*)d_in[5];
    float* out = (float*)d_out;

    char* ws = (char*)d_ws;
    float4* xyzw = (float4*)ws;                               // 512 KB
    float*  vfeat = (float*)(ws + (512 << 10));               // 8 MB
    int*    idxw  = (int*)(ws + (512 << 10) + (8 << 20));     // 4.5 MB

    k_vfeat<<<NPTS / 32, 256, 0, stream>>>(feat, xyz, Wv, bv, vfeat, xyzw);
    k_knn  <<<NPTS / 64, 1024, 0, stream>>>(xyzw, idxw);
    k_att  <<<NPTS / 4, 256, 0, stream>>>(feat, vfeat, idxw, Wsuf, bsuf, out);
}

// Round 4
// 321.822 us; speedup vs baseline: 2.0179x; 1.0362x over previous
//
#include <hip/hip_runtime.h>
#include <stdint.h>
#include <limits.h>

// Problem constants (reference: B=4, N=8192, C=64, OUT=64, KNN=36)
#define BB 4
#define NN 8192
#define CC 64
#define OUTD 64
#define KK 36
#define NPTS (BB * NN)          // 32768
#define NBIN 129                // bins 0..128 (0 and 128 are clamp catch-alls)
// t = signed(float_bits(d2)) >> 20 (arith); bin = med3_i32(t,960,1088) - 960.
// Negative d2 (fp rounding near 0) -> t very negative -> bin 0. No fmax needed.

static __device__ __forceinline__ int laneid() { return threadIdx.x & 63; }
static __device__ __forceinline__ int waveid_uniform() {
    return __builtin_amdgcn_readfirstlane((int)(threadIdx.x >> 6));
}

// ---------------------------------------------------------------------------
// Kernel 1: v_feat = relu([feature, xyz] @ W_v + b_v)  and pack xyzw=(x,y,z,|p|^2)
// One wave handles 8 points (shares each Wv row load across 8 accumulators).
// Block = 256 = 4 waves = 32 points. grid = NPTS/32 = 1024 blocks.
// ---------------------------------------------------------------------------
__global__ __launch_bounds__(256) void k_vfeat(
    const float* __restrict__ feat, const float* __restrict__ xyz,
    const float* __restrict__ Wv, const float* __restrict__ bv,
    float* __restrict__ vfeat, float4* __restrict__ xyzw)
{
    __shared__ float fb[4][8][64];
    __shared__ float xb[4][8][3];
    const int lane = laneid();
    const int wv = waveid_uniform();
    const int pbase = blockIdx.x * 32 + wv * 8;

    #pragma unroll
    for (int pp = 0; pp < 8; ++pp)
        fb[wv][pp][lane] = feat[(pbase + pp) * CC + lane];
    if (lane < 24)
        xb[wv][lane / 3][lane % 3] = xyz[pbase * 3 + lane];
    // same-wave LDS write->read: in-order per wave, compiler inserts lgkmcnt

    const float b0 = bv[lane];
    float acc[8];
    #pragma unroll
    for (int pp = 0; pp < 8; ++pp) acc[pp] = b0;

    #pragma unroll 4
    for (int c = 0; c < CC; ++c) {
        float w = Wv[c * OUTD + lane];
        #pragma unroll
        for (int pp = 0; pp < 8; ++pp)
            acc[pp] = fmaf(fb[wv][pp][c], w, acc[pp]);
    }
    const float wx = Wv[64 * OUTD + lane];
    const float wy = Wv[65 * OUTD + lane];
    const float wz = Wv[66 * OUTD + lane];
    #pragma unroll
    for (int pp = 0; pp < 8; ++pp) {
        float a = acc[pp];
        a = fmaf(xb[wv][pp][0], wx, a);
        a = fmaf(xb[wv][pp][1], wy, a);
        a = fmaf(xb[wv][pp][2], wz, a);
        vfeat[(pbase + pp) * OUTD + lane] = fmaxf(a, 0.0f);
    }
    if (lane < 8) {
        float x = xb[wv][lane][0], y = xb[wv][lane][1], z = xb[wv][lane][2];
        float sq = (x * x + y * y) + z * z;
        xyzw[pbase + lane] = make_float4(x, y, z, sq);
    }
}

// ---------------------------------------------------------------------------
// Kernel 2: 36-NN via per-query float-bit histogram selection.
// Block = 1024 threads = 16 waves sharing the SAME 64 queries (lane = query),
// each wave scans a 512-candidate segment. grid = NPTS/64 = 512 blocks.
// Pass 1: ~9 VALU/candidate (signed-shift + med3 binning, fused addressing).
// Pass 2: ~9 VALU/candidate (pure integer threshold compares, no bin calc).
// Tie-break matches lax.top_k: (distance-bits, then smaller index).
// ---------------------------------------------------------------------------
__global__ __launch_bounds__(1024) void k_knn(
    const float4* __restrict__ xyzw, int* __restrict__ idx_ws)
{
    __shared__ __align__(16) uint32_t hist[NBIN * 64];  // 33 KB; reused as buf in pass 2
    __shared__ int binB[64];
    __shared__ int cumLoA[64];
    __shared__ uint32_t bufCnt[64];
    __shared__ uint32_t dirCnt[64];

    const int lane = laneid();
    const int wv = waveid_uniform();               // 0..15
    const int batch = blockIdx.x >> 7;             // 128 blocks per batch
    const int qbase = (blockIdx.x & 127) << 6;
    const int q = qbase + lane;                    // local query id 0..8191
    const float4* __restrict__ xw = xyzw + batch * NN;

    const float4 Q = xw[q];
    const int laneAdj = lane - 960 * 64;           // fold bin rebase into addressing

    for (int i = threadIdx.x; i < NBIN * 64; i += 1024) hist[i] = 0u;
    if (threadIdx.x < 64) { bufCnt[threadIdx.x] = 0u; dirCnt[threadIdx.x] = 0u; }
    __syncthreads();

    const int j0 = wv * 512;

    // ---- pass 1: histogram of distance bits ----
    #pragma unroll 4
    for (int j = j0; j < j0 + 512; ++j) {
        float4 Cd = xw[j];                         // wave-uniform -> s_load_dwordx4
        float dot = fmaf(Q.x, Cd.x, fmaf(Q.y, Cd.y, Q.z * Cd.z));
        float d = fmaf(-2.0f, dot, Q.w + Cd.w);
        int t = ((int)__float_as_uint(d)) >> 20;   // arith shift: neg d -> very neg
        int m3 = min(max(t, 960), 1088);           // v_med3_i32
        atomicAdd(&hist[m3 * 64 + laneAdj], 1u);   // == hist[bin*64 + lane]
    }
    __syncthreads();

    // ---- find crossing bin (threads 0..63, one query each) ----
    if (threadIdx.x < 64) {
        int cum = 0, Bq = 128, cl = 0;
        for (int b2 = 0; b2 < NBIN; ++b2) {
            int c = (int)hist[b2 * 64 + threadIdx.x];
            if (cum + c >= KK) { Bq = b2; cl = cum; break; }
            cum += c;
        }
        binB[threadIdx.x] = Bq;
        cumLoA[threadIdx.x] = cl;
    }
    __syncthreads();

    // ---- per-lane integer thresholds for pass 2 ----
    // bin <  Bq  <=>  t < tLt            (Bq==0: never)
    // bin == Bq  <=>  tEqLo <= t <= tEqHi (clamp edges folded into sentinels)
    const int Bq = binB[lane];
    const int tLt   = (Bq > 0)   ? (960 + Bq) : INT_MIN;
    const int tEqLo = (Bq == 0)  ? INT_MIN    : (960 + Bq);
    const int tEqHi = (Bq == 128) ? INT_MAX   : (960 + Bq);
    const int grow = batch * NN + q;

    // buf[pos][lane] (transposed): 64 pos x 64 lanes x 8B = 32 KB (inside hist)
    unsigned long long* buf = (unsigned long long*)hist;

    // ---- pass 2: direct-emit strict members; buffer boundary-bin members ----
    #pragma unroll 4
    for (int j = j0; j < j0 + 512; ++j) {
        float4 Cd = xw[j];
        float dot = fmaf(Q.x, Cd.x, fmaf(Q.y, Cd.y, Q.z * Cd.z));
        float d = fmaf(-2.0f, dot, Q.w + Cd.w);
        int t = ((int)__float_as_uint(d)) >> 20;
        if (t < tLt) {
            uint32_t pos = atomicAdd(&dirCnt[lane], 1u);
            idx_ws[grow * KK + (int)pos] = batch * NN + j;   // pos < cumLo < 36
        } else if (t >= tEqLo && t <= tEqHi) {
            uint32_t db = __float_as_uint(fmaxf(d, 0.0f));   // exact monotone key
            uint32_t pos = atomicAdd(&bufCnt[lane], 1u);
            if (pos < 64u) buf[(int)pos * 64 + lane] =
                ((unsigned long long)db << 32) | (uint32_t)j;
        }
    }
    __syncthreads();

    // ---- final: pick (36 - cumLo) smallest exact keys from boundary bin ----
    if (threadIdx.x < 64) {
        const int t = threadIdx.x;
        const int q2 = qbase + t;
        const int grow2 = batch * NN + q2;
        const int cl = cumLoA[t];
        const int r = KK - cl;
        const int M = min((int)bufCnt[t], 64);
        const int outp = grow2 * KK + cl;
        for (int i = 0; i < r; ++i) {
            unsigned long long best = ~0ULL; int bi = -1;
            for (int u = 0; u < M; ++u) {
                unsigned long long v = buf[u * 64 + t];
                if (v < best) { best = v; bi = u; }
            }
            int jj;
            if (bi >= 0) { buf[bi * 64 + t] = ~0ULL; jj = (int)(best & 0xFFFFFFFFu); }
            else jj = q2;                            // pathological fallback
            if (jj < 0 || jj >= NN) jj = q2;
            idx_ws[outp + i] = batch * NN + jj;
        }
    }
}

// ---------------------------------------------------------------------------
// Kernel 3: attention. One wave per point. Indices preloaded as 9 x int4
// (register-resident, fully unrolled) so gather loops have no serial s_load
// dependency. G staged in LDS stride-65 (conflict-free); 36 parallel logits;
// one butterfly max + sum; weighted-V gather; 64x64 projection.
// grid = NPTS/4 blocks of 256. No __syncthreads (waves independent).
// ---------------------------------------------------------------------------
#define IDX(k) (((k) & 3) == 0 ? I[(k) >> 2].x : ((k) & 3) == 1 ? I[(k) >> 2].y : \
                ((k) & 3) == 2 ? I[(k) >> 2].z : I[(k) >> 2].w)

__global__ __launch_bounds__(256) void k_att(
    const float* __restrict__ feat, const float* __restrict__ vfeat,
    const int* __restrict__ idxw, const float* __restrict__ Wsuf,
    const float* __restrict__ bsuf, float* __restrict__ out)
{
    __shared__ float G[4][KK][65];   // 37,440 B
    __shared__ float F[4][64];
    __shared__ float Wb[4][KK];
    __shared__ float accb[4][64];
    const int lane = laneid();
    const int wv = waveid_uniform();
    const int p = blockIdx.x * 4 + wv;

    // preload all 36 neighbor indices (KK*4 = 144 B, 16B-aligned for every p)
    const int4* __restrict__ myidx4 = (const int4*)(idxw + p * KK);
    int4 I[9];
    #pragma unroll
    for (int t = 0; t < 9; ++t) I[t] = myidx4[t];

    const float f = feat[p * CC + lane];
    F[wv][lane] = f;

    #pragma unroll
    for (int k = 0; k < KK; ++k) {
        int j = IDX(k);
        G[wv][k][lane] = feat[j * CC + lane];      // coalesced row gather
    }

    // logits: lane k (<36) sums over channels; G stride 65 = bank-conflict-free
    float logit = -1e30f;
    if (lane < KK) {
        float a = 0.0f;
        #pragma unroll 8
        for (int c = 0; c < CC; ++c)
            a = fmaf(F[wv][c], G[wv][lane][c], a);
        logit = a;
    }
    // softmax across the 36 logit lanes (others contribute -inf / 0)
    float m = logit;
    #pragma unroll
    for (int off = 32; off > 0; off >>= 1)
        m = fmaxf(m, __shfl_xor(m, off, 64));
    float e = (lane < KK) ? __expf(logit - m) : 0.0f;
    float s = e;
    #pragma unroll
    for (int off = 32; off > 0; off >>= 1)
        s += __shfl_xor(s, off, 64);
    if (lane < KK) Wb[wv][lane] = e / s;

    // weighted V gather: lane = channel
    float acc = 0.0f;
    #pragma unroll
    for (int k = 0; k < KK; ++k) {
        int j = IDX(k);
        acc = fmaf(Wb[wv][k], vfeat[j * OUTD + lane], acc);
    }
    accb[wv][lane] = acc;

    float o = bsuf[lane];
    #pragma unroll 8
    for (int c = 0; c < OUTD; ++c)
        o = fmaf(accb[wv][c], Wsuf[c * OUTD + lane], o);
    out[p * OUTD + lane] = o;

    if (p == 0 && lane == 0) out[NPTS * OUTD] = (float)NN;  // output 1: scalar N
}

// ---------------------------------------------------------------------------
extern "C" void kernel_launch(void* const* d_in, const int* in_sizes, int n_in,
                              void* d_out, int out_size, void* d_ws, size_t ws_size,
                              hipStream_t stream)
{
    const float* feat = (const float*)d_in[0];
    const float* xyz  = (const float*)d_in[1];
    const float* Wv   = (const float*)d_in[2];
    const float* bv   = (const float*)d_in[3];
    const float* Wsuf = (const float*)d_in[4];
    const float* bsuf = (const float*)d_in[5];
    float* out = (float*)d_out;

    char* ws = (char*)d_ws;
    float4* xyzw = (float4*)ws;                               // 512 KB
    float*  vfeat = (float*)(ws + (512 << 10));               // 8 MB
    int*    idxw  = (int*)(ws + (512 << 10) + (8 << 20));     // 4.5 MB

    k_vfeat<<<NPTS / 32, 256, 0, stream>>>(feat, xyz, Wv, bv, vfeat, xyzw);
    k_knn  <<<NPTS / 64, 1024, 0, stream>>>(xyzw, idxw);
    k_att  <<<NPTS / 4, 256, 0, stream>>>(feat, vfeat, idxw, Wsuf, bsuf, out);
}